// Round 13
// baseline (162.121 us; speedup 1.0000x reference)
//
#include <hip/hip_runtime.h>

// VectorQuantizer: x [2,8,48,48,48] f32, embed [512,8] f32
// d_out: loss (1) | out (1769472) | encodings (221184*512 = 113246208)
// R13: argmin WITHOUT LDS in the hot loop -- codebook lives in per-lane
// registers (lane j: rows 8j..8j+7 + norms), broadcast via v_readlane with
// uniform source lane; ~21 VALU/row, VALU-bound ~30us (vs 74us LDS-bound).
// Then R4's PROVEN full-rate store phase (one-hot embedded dense sweep).

#pragma clang fp contract(off)

#define KCB   512
#define SPB   110592          // 48^3
#define NBLK  864             // 256 points per block
#define OUT_OFF 1
#define ENC_OFF 1769473LL     // 1 + 2*8*SPB ; %4 == 1
#define G4_BASE 442369LL      // (ENC_OFF + 3) / 4

__device__ __forceinline__ float rdlane(float v, int lane) {
    return __int_as_float(__builtin_amdgcn_readlane(__float_as_int(v), lane));
}

__global__ __launch_bounds__(256) void vq_main(const float* __restrict__ x,
                                               const float* __restrict__ e,
                                               float* __restrict__ dout,
                                               float* __restrict__ partials) {
    __shared__ int   sidx[256];
    __shared__ float sred[256];
    const int t   = threadIdx.x;
    const int L   = t & 63;                        // lane
    const int blk = blockIdx.x;
    const int b   = (blk >= 432) ? 1 : 0;          // blocks don't straddle batch
    const int s   = blk * 256 - b * SPB + t;       // this thread's spatial index

    // x loads early (coalesced per channel)
    const float* xb = x + (size_t)b * (8 * SPB) + s;
    float xv[8];
    #pragma unroll
    for (int c = 0; c < 8; ++c) xv[c] = xb[(size_t)c * SPB];

    // register codebook: lane L holds rows 8L..8L+7 (64 regs) + norms (8 regs)
    float cbr[8][8];
    float nrm[8];
    {
        const float4* ep = (const float4*)e + (L << 4);   // 16 float4 = 8 rows
        #pragma unroll
        for (int r = 0; r < 8; ++r) {
            float4 lo = ep[r * 2], hi = ep[r * 2 + 1];
            cbr[r][0] = lo.x; cbr[r][1] = lo.y; cbr[r][2] = lo.z; cbr[r][3] = lo.w;
            cbr[r][4] = hi.x; cbr[r][5] = hi.y; cbr[r][6] = hi.z; cbr[r][7] = hi.w;
            // numpy 8-elem pairwise tree (contract off: squares round first)
            nrm[r] = ((lo.x*lo.x + lo.y*lo.y) + (lo.z*lo.z + lo.w*lo.w))
                   + ((hi.x*hi.x + hi.y*hi.y) + (hi.z*hi.z + hi.w*hi.w));
        }
    }

    // sum(x^2), numpy tree
    float sx = ((xv[0]*xv[0] + xv[1]*xv[1]) + (xv[2]*xv[2] + xv[3]*xv[3]))
             + ((xv[4]*xv[4] + xv[5]*xv[5]) + (xv[6]*xv[6] + xv[7]*xv[7]));

    // argmin_k fl( fl(sx+se_k) - 2*dot_k ); single chain, strict < = first min.
    float best = 3.402823466e38f;
    int   bidx = 0;
    #pragma unroll 1
    for (int i = 0; i < 64; ++i) {                 // uniform source lane
        #pragma unroll
        for (int r = 0; r < 8; ++r) {              // constant reg index after unroll
            float se = rdlane(nrm[r], i);
            float ssk = sx + se;                   // rounded add, matches ref
            float dot =        xv[0] * rdlane(cbr[r][0], i);
            dot = __builtin_fmaf(xv[1], rdlane(cbr[r][1], i), dot);
            dot = __builtin_fmaf(xv[2], rdlane(cbr[r][2], i), dot);
            dot = __builtin_fmaf(xv[3], rdlane(cbr[r][3], i), dot);
            dot = __builtin_fmaf(xv[4], rdlane(cbr[r][4], i), dot);
            dot = __builtin_fmaf(xv[5], rdlane(cbr[r][5], i), dot);
            dot = __builtin_fmaf(xv[6], rdlane(cbr[r][6], i), dot);
            dot = __builtin_fmaf(xv[7], rdlane(cbr[r][7], i), dot);
            float d = __builtin_fmaf(-2.0f, dot, ssk);   // == fl(ssk - 2*dot)
            bool lt = d < best;
            best = lt ? d : best;
            bidx = lt ? (i * 8 + r) : bidx;
        }
    }

    sidx[t] = bidx;
    __syncthreads();

    // ---- store phase: dense one-hot sweep of this block's 512KB region ----
    // (R4-proven structure/rate: 3 head floats, 32767 aligned f4, 1 tail.)
    float4* o4 = (float4*)dout;
    float*  encf = dout + (ENC_OFF + (long long)blk * 131072);
    const long long g4_start = G4_BASE + (long long)blk * 32768;
    #pragma unroll 1
    for (int i = 0; i < 128; ++i) {
        int t_lin = i * 256 + t;
        if (t_lin < 32767) {
            int f  = 3 + (t_lin << 2);   // float index within block's enc region
            int nl = f >> 9;             // local row 0..255
            int k0 = f & 511;
            int id0 = sidx[nl];
            float4 v;
            if (k0 != 511) {
                v.x = (id0 == k0    ) ? 1.0f : 0.0f;
                v.y = (id0 == k0 + 1) ? 1.0f : 0.0f;
                v.z = (id0 == k0 + 2) ? 1.0f : 0.0f;
                v.w = (id0 == k0 + 3) ? 1.0f : 0.0f;
            } else {                      // crosses a row boundary
                int id1 = sidx[nl + 1];
                v.x = (id0 == 511) ? 1.0f : 0.0f;
                v.y = (id1 == 0  ) ? 1.0f : 0.0f;
                v.z = (id1 == 1  ) ? 1.0f : 0.0f;
                v.w = (id1 == 2  ) ? 1.0f : 0.0f;
            }
            o4[g4_start + t_lin] = v;
        }
    }
    if (t < 3) {
        int id = sidx[0];
        encf[t] = (id == t) ? 1.0f : 0.0f;         // head: cols 0..2 of row 0
    } else if (t == 3) {
        int id = sidx[255];
        encf[131071] = (id == 511) ? 1.0f : 0.0f;  // tail: col 511 of row 255
    }

    // out region + loss partial (codebook row via global gather, L1/L2-hot)
    const float4* q4 = (const float4*)(e + (bidx << 3));
    float4 qa = q4[0], qb = q4[1];
    float qv[8] = {qa.x, qa.y, qa.z, qa.w, qb.x, qb.y, qb.z, qb.w};
    float part = 0.0f;
    float* outp = dout + OUT_OFF + (size_t)b * (8 * SPB) + s;
    #pragma unroll
    for (int c = 0; c < 8; ++c) {
        float dq = qv[c] - xv[c];
        part += dq * dq;
        outp[(size_t)c * SPB] = qv[c];
    }

    // deterministic block reduction
    sred[t] = part;
    __syncthreads();
    for (int off = 128; off > 0; off >>= 1) {
        if (t < off) sred[t] += sred[t + off];
        __syncthreads();
    }
    if (t == 0) partials[blk] = sred[0];
}

__global__ __launch_bounds__(256) void loss_kernel(const float* __restrict__ partials,
                                                   float* __restrict__ dout) {
    __shared__ float sred[256];
    int t = threadIdx.x;
    float a = 0.0f;
    for (int j = t; j < NBLK; j += 256) a += partials[j];  // fixed order
    sred[t] = a;
    __syncthreads();
    for (int off = 128; off > 0; off >>= 1) {
        if (t < off) sred[t] += sred[t + off];
        __syncthreads();
    }
    if (t == 0) {
        float m = sred[0] / 1769472.0f;
        m = fminf(fmaxf(m, 0.0f), 10.0f);
        dout[0] = m + 0.25f * m;   // q_latent + beta*e_latent (equal values)
    }
}

extern "C" void kernel_launch(void* const* d_in, const int* in_sizes, int n_in,
                              void* d_out, int out_size, void* d_ws, size_t ws_size,
                              hipStream_t stream) {
    const float* x = (const float*)d_in[0];
    const float* e = (const float*)d_in[1];
    float* dout     = (float*)d_out;
    float* partials = (float*)d_ws;     // 864 floats

    hipLaunchKernelGGL(vq_main,     dim3(NBLK), dim3(256), 0, stream, x, e, dout, partials);
    hipLaunchKernelGGL(loss_kernel, dim3(1),    dim3(256), 0, stream, partials, dout);
}